// Round 10
// baseline (1373.822 us; speedup 1.0000x reference)
//
#include <hip/hip_runtime.h>

constexpr int LDIM  = 128;
constexpr int NNODE = 20000;
constexpr int EM_N  = 100000;
constexpr int EW_N  = 25000;
constexpr int NSTEP = 6;

typedef short bf16x8 __attribute__((ext_vector_type(8)));
typedef float f32x4  __attribute__((ext_vector_type(4)));

struct MlpParams {
  const float* x;
  const float* attrIn;
  float*       attrOut;
  const int*   src;
  const int*   dst;
  float*       sum1;    // edge: scatter target; node: mesh sum (zeroed after read)
  float*       sum2;    // node: world sum (zeroed after read)
  const float* inv1;
  const float* inv2;
  const short* W1H;     // bf16 [128 n][384 k]
  const short* W2H;     // bf16 [128 n][128 k]
  const float* b1;
  const float* b2;
  const float* gam;
  const float* bet;
  int nRows;
};

__device__ __forceinline__ short f2b(float f) {
  unsigned int u = __float_as_uint(f);
  u = (u + 0x7fffu + ((u >> 16) & 1u)) >> 16;
  return (short)u;
}

__device__ __forceinline__ unsigned int cvtpk(float lo, float hi) {
  unsigned int r;
  asm("v_cvt_pk_bf16_f32 %0, %1, %2" : "=v"(r) : "v"(lo), "v"(hi));
  return r;
}
__device__ __forceinline__ bf16x8 pack8(float4 a, float4 b) {
  union { unsigned int u[4]; bf16x8 s; } x;
  x.u[0] = cvtpk(a.x, a.y); x.u[1] = cvtpk(a.z, a.w);
  x.u[2] = cvtpk(b.x, b.y); x.u[3] = cvtpk(b.z, b.w);
  return x.s;
}

// WAVE-INDEPENDENT MLP: each wave computes 16 rows x 128 cols end-to-end with
// ZERO inter-wave synchronization (R6/R8/R9 showed the block-cooperative
// barrier structure plateaus at ~130us regardless of occupancy/barrier tweaks).
// A: per-lane global gather + v_cvt_pk_bf16_f32 into the MFMA fragment.
// W1/W2: per-lane fragments direct from global (L2-resident, shared by all).
// H: transposed through a wave-PRIVATE padded LDS slice (intra-wave ds only).
// LN: in-wave shuffle reduce. No __syncthreads anywhere.
template<bool IS_EDGE>
__launch_bounds__(256, 3)
__global__ void mlp_kernel(MlpParams pmA, MlpParams pmB, int blocksA) {
  __shared__ __align__(16) short HwAll[4][16][136];  // 17 KB; [136] => 2-way banks (free)

  const int t   = threadIdx.x;
  const int wid = t >> 6, l = t & 63;
  const int lr  = l & 15,  lg = l >> 4;
  short (*Hw)[136] = HwAll[wid];

  const bool isA = (int)blockIdx.x < blocksA;
  const MlpParams P = isA ? pmA : pmB;
  const int bid  = isA ? (int)blockIdx.x : (int)blockIdx.x - blocksA;
  const int r0   = bid * 64 + wid * 16;

  // this lane's A-gather row (rows are independent in C[i,:] = A[i,:]*W:
  // clamped tail lanes compute garbage rows that are never stored)
  const int  arow = min(r0 + lr, P.nRows - 1);
  const bool aval = (r0 + lr) < P.nRows;

  const float* base0; const float* base1; const float* base2;
  float sc1 = 1.f, sc2 = 1.f;
  if (IS_EDGE) {
    base0 = P.x + (size_t)P.src[arow] * LDIM;
    base1 = P.x + (size_t)P.dst[arow] * LDIM;
    base2 = P.attrIn + (size_t)arow * LDIM;
  } else {
    base0 = P.x    + (size_t)arow * LDIM;
    base1 = P.sum1 + (size_t)arow * LDIM;
    base2 = P.sum2 + (size_t)arow * LDIM;
    sc1 = P.inv1[arow];
    sc2 = P.inv2[arow];
  }

  // ---------------- phase 1: H = relu(A @ W1 + b1), K = 384 ----------------
  const short* w1p = P.W1H + (size_t)lr * 384 + lg * 8;  // + ct*16*384 + kc*32
  f32x4 acc[8];
#pragma unroll
  for (int i = 0; i < 8; ++i) acc[i] = f32x4{0.f, 0.f, 0.f, 0.f};

#pragma unroll
  for (int kc = 0; kc < 12; ++kc) {
    const int seg = kc >> 2, part = kc & 3;
    const float* ab = (seg == 0 ? base0 : seg == 1 ? base1 : base2) + part * 32 + lg * 8;
    float4 a0 = *(const float4*)ab;
    float4 a1 = *(const float4*)(ab + 4);
    if constexpr (!IS_EDGE) {
      if (seg != 0) {
        const float sc = (seg == 1) ? sc1 : sc2;
        a0.x *= sc; a0.y *= sc; a0.z *= sc; a0.w *= sc;
        a1.x *= sc; a1.y *= sc; a1.z *= sc; a1.w *= sc;
        if (aval) {   // zero-after-read (each element owned by exactly one lane)
          float4 z = {0.f, 0.f, 0.f, 0.f};
          ((float4*)ab)[0] = z; ((float4*)ab)[1] = z;
        }
      }
    }
    const bf16x8 af = pack8(a0, a1);
#pragma unroll
    for (int ct = 0; ct < 8; ++ct) {
      const bf16x8 bf = *(const bf16x8*)(w1p + (size_t)ct * (16 * 384) + kc * 32);
      acc[ct] = __builtin_amdgcn_mfma_f32_16x16x32_bf16(af, bf, acc[ct], 0, 0, 0);
    }
  }

  // H = relu(acc + b1) -> wave-private LDS (transpose C-layout -> A-layout)
#pragma unroll
  for (int ct = 0; ct < 8; ++ct) {
    const int cc = ct * 16 + lr;
    const float bb = P.b1[cc];
#pragma unroll
    for (int q = 0; q < 4; ++q)
      Hw[lg * 4 + q][cc] = f2b(fmaxf(acc[ct][q] + bb, 0.f));
  }

  // ---------------- phase 2: OUT = H @ W2 + b2, K = 128 ----------------
  const short* w2p = P.W2H + (size_t)lr * 128 + lg * 8;
  f32x4 acc2[8];
#pragma unroll
  for (int i = 0; i < 8; ++i) acc2[i] = f32x4{0.f, 0.f, 0.f, 0.f};

#pragma unroll
  for (int kc = 0; kc < 4; ++kc) {
    const bf16x8 hf = *(const bf16x8*)&Hw[lr][kc * 32 + lg * 8];
#pragma unroll
    for (int ct = 0; ct < 8; ++ct) {
      const bf16x8 bf = *(const bf16x8*)(w2p + (size_t)ct * (16 * 128) + kc * 32);
      acc2[ct] = __builtin_amdgcn_mfma_f32_16x16x32_bf16(hf, bf, acc2[ct], 0, 0, 0);
    }
  }

  // ---------------- f32 epilogue: b2 + in-wave LN ----------------
  float bv[8], gv[8], bev[8];
#pragma unroll
  for (int ct = 0; ct < 8; ++ct) {
    const int cc = ct * 16 + lr;
    bv[ct] = P.b2[cc]; gv[ct] = P.gam[cc]; bev[ct] = P.bet[cc];
  }
  float s1a[4] = {0.f, 0.f, 0.f, 0.f};
  float s2a[4] = {0.f, 0.f, 0.f, 0.f};
#pragma unroll
  for (int ct = 0; ct < 8; ++ct)
#pragma unroll
    for (int q = 0; q < 4; ++q) {
      const float v = acc2[ct][q] + bv[ct];
      acc2[ct][q] = v;
      s1a[q] += v; s2a[q] += v * v;
    }
#pragma unroll
  for (int m = 1; m < 16; m <<= 1) {
#pragma unroll
    for (int q = 0; q < 4; ++q) {
      s1a[q] += __shfl_xor(s1a[q], m);
      s2a[q] += __shfl_xor(s2a[q], m);
    }
  }

  // normalize + residual + store + (edge) scatter-add; lane owns rows lg*4+q
#pragma unroll
  for (int q = 0; q < 4; ++q) {
    const int grow = r0 + lg * 4 + q;
    if (grow < P.nRows) {
      const float mu  = s1a[q] * (1.0f / 128.0f);
      const float var = s2a[q] * (1.0f / 128.0f) - mu * mu;
      const float rs  = rsqrtf(var + 1e-5f);
      const float* rin  = P.attrIn  + (size_t)grow * LDIM;
      float*       rout = P.attrOut + (size_t)grow * LDIM;
      float* ssum = nullptr;
      if (IS_EDGE) ssum = P.sum1 + (size_t)P.dst[grow] * LDIM;
#pragma unroll
      for (int ct = 0; ct < 8; ++ct) {
        const int cc = ct * 16 + lr;
        const float o = gv[ct] * (acc2[ct][q] - mu) * rs + bev[ct] + rin[cc];
        rout[cc] = o;
        if (IS_EDGE) atomicAdd(ssum + cc, o);
      }
    }
  }
}

// ---- prep kernels ----
__global__ void prep_weights(const float* w1a, const float* w1b, const float* w1c,
                             const float* w2a, const float* w2b, const float* w2c,
                             short* w1h, short* w2h) {
  int i = blockIdx.x * 256 + threadIdx.x;
  constexpr int N1 = 18 * 128 * 384;
  constexpr int N2 = 18 * 128 * 128;
  if (i < N1) {
    int g = i / (128 * 384);
    int rem = i - g * (128 * 384);
    int n = rem / 384, k = rem - n * 384;
    int m = g / 6, s = g - m * 6;
    const float* src = (m == 0) ? w1a : (m == 1) ? w1b : w1c;
    w1h[i] = f2b(src[(size_t)s * (384 * 128) + (size_t)k * 128 + n]);
  } else if (i < N1 + N2) {
    int j = i - N1;
    int g = j / (128 * 128);
    int rem = j - g * (128 * 128);
    int n = rem / 128, k = rem - n * 128;
    int m = g / 6, s = g - m * 6;
    const float* src = (m == 0) ? w2a : (m == 1) ? w2b : w2c;
    w2h[j] = f2b(src[(size_t)s * (128 * 128) + (size_t)k * 128 + n]);
  }
}

__global__ void prep_deg(const int* mr, const int* wrcv, int* degm, int* degw) {
  int i = blockIdx.x * 256 + threadIdx.x;
  if (i < EM_N) atomicAdd(&degm[mr[i]], 1);
  else if (i < EM_N + EW_N) atomicAdd(&degw[wrcv[i - EM_N]], 1);
}

__global__ void prep_inv(const int* degm, const int* degw, float* invm, float* invw) {
  int i = blockIdx.x * 256 + threadIdx.x;
  if (i < NNODE) {
    invm[i] = 1.0f / fmaxf((float)degm[i], 1.0f);
    invw[i] = 1.0f / fmaxf((float)degw[i], 1.0f);
  }
}

extern "C" void kernel_launch(void* const* d_in, const int* in_sizes, int n_in,
                              void* d_out, int out_size, void* d_ws, size_t ws_size,
                              hipStream_t stream) {
  (void)in_sizes; (void)n_in; (void)out_size; (void)ws_size;
  const float* x_in   = (const float*)d_in[0];
  const float* mea_in = (const float*)d_in[1];
  const float* wea_in = (const float*)d_in[2];
  const int*   mei    = (const int*)d_in[3];
  const int*   wei    = (const int*)d_in[4];
  const float* W1s[3] = { (const float*)d_in[5],  (const float*)d_in[11], (const float*)d_in[17] };
  const float* B1s[3] = { (const float*)d_in[6],  (const float*)d_in[12], (const float*)d_in[18] };
  const float* W2s[3] = { (const float*)d_in[7],  (const float*)d_in[13], (const float*)d_in[19] };
  const float* B2s[3] = { (const float*)d_in[8],  (const float*)d_in[14], (const float*)d_in[20] };
  const float* Gs[3]  = { (const float*)d_in[9],  (const float*)d_in[15], (const float*)d_in[21] };
  const float* Be[3]  = { (const float*)d_in[10], (const float*)d_in[16], (const float*)d_in[22] };

  float* xo  = (float*)d_out;
  float* meo = xo  + (size_t)NNODE * LDIM;
  float* weo = meo + (size_t)EM_N * LDIM;

  float* msum = (float*)d_ws;
  float* wsum = msum + (size_t)NNODE * LDIM;
  int*   degm = (int*)(wsum + (size_t)NNODE * LDIM);
  int*   degw = degm + NNODE;
  float* invm = (float*)(degw + NNODE);
  float* invw = invm + NNODE;
  short* w1h  = (short*)(invw + NNODE);
  short* w2h  = w1h + (size_t)18 * 128 * 384;

  size_t zbytes = (size_t)2 * NNODE * LDIM * 4 + (size_t)2 * NNODE * 4;
  hipMemsetAsync(d_ws, 0, zbytes, stream);

  {
    int tot = 18 * 128 * 384 + 18 * 128 * 128;
    prep_weights<<<dim3((tot + 255) / 256), 256, 0, stream>>>(
        W1s[0], W1s[1], W1s[2], W2s[0], W2s[1], W2s[2], w1h, w2h);
  }
  prep_deg<<<dim3((EM_N + EW_N + 255) / 256), 256, 0, stream>>>(mei + EM_N, wei + EW_N, degm, degw);
  prep_inv<<<dim3((NNODE + 255) / 256), 256, 0, stream>>>(degm, degw, invm, invw);

  const int MB = (EM_N + 63) / 64;   // 1563
  const int WB = (EW_N + 63) / 64;   // 391
  const int NB = (NNODE + 63) / 64;  // 313

  const float* xc = x_in;
  const float* mc = mea_in;
  const float* wc = wea_in;

  for (int s = 0; s < NSTEP; ++s) {
    MlpParams pm{}, pw{}, pn{};

    pm.x = xc; pm.attrIn = mc; pm.attrOut = meo;
    pm.src = mei; pm.dst = mei + EM_N;
    pm.sum1 = msum;
    pm.W1H = w1h + (size_t)(0 * 6 + s) * 128 * 384;
    pm.W2H = w2h + (size_t)(0 * 6 + s) * 128 * 128;
    pm.b1 = B1s[0] + s * LDIM; pm.b2 = B2s[0] + s * LDIM;
    pm.gam = Gs[0] + s * LDIM; pm.bet = Be[0] + s * LDIM;
    pm.nRows = EM_N;

    pw.x = xc; pw.attrIn = wc; pw.attrOut = weo;
    pw.src = wei; pw.dst = wei + EW_N;
    pw.sum1 = wsum;
    pw.W1H = w1h + (size_t)(1 * 6 + s) * 128 * 384;
    pw.W2H = w2h + (size_t)(1 * 6 + s) * 128 * 128;
    pw.b1 = B1s[1] + s * LDIM; pw.b2 = B2s[1] + s * LDIM;
    pw.gam = Gs[1] + s * LDIM; pw.bet = Be[1] + s * LDIM;
    pw.nRows = EW_N;

    mlp_kernel<true><<<dim3(MB + WB), 256, 0, stream>>>(pm, pw, MB);

    pn.x = xc; pn.attrIn = xc; pn.attrOut = xo;
    pn.sum1 = msum; pn.sum2 = wsum; pn.inv1 = invm; pn.inv2 = invw;
    pn.W1H = w1h + (size_t)(2 * 6 + s) * 128 * 384;
    pn.W2H = w2h + (size_t)(2 * 6 + s) * 128 * 128;
    pn.b1 = B1s[2] + s * LDIM; pn.b2 = B2s[2] + s * LDIM;
    pn.gam = Gs[2] + s * LDIM; pn.bet = Be[2] + s * LDIM;
    pn.nRows = NNODE;

    mlp_kernel<false><<<dim3(NB), 256, 0, stream>>>(pn, pn, NB);

    xc = xo; mc = meo; wc = weo;
  }
}

// Round 11
// 939.790 us; speedup vs baseline: 1.4618x; 1.4618x over previous
//
#include <hip/hip_runtime.h>

constexpr int LDIM  = 128;
constexpr int NNODE = 20000;
constexpr int EM_N  = 100000;
constexpr int EW_N  = 25000;
constexpr int NSTEP = 6;

typedef short bf16x8 __attribute__((ext_vector_type(8)));
typedef float f32x4  __attribute__((ext_vector_type(4)));

struct MlpParams {
  const float* x;
  const float* attrIn;
  float*       attrOut;
  const int*   src;
  const int*   dst;
  float*       sum1;    // edge: scatter target; node: mesh sum (zeroed after read)
  float*       sum2;    // node: world sum (zeroed after read)
  const float* inv1;
  const float* inv2;
  const short* W1H;     // bf16 [128 n][384 k]
  const short* W2H;     // bf16 [128 n][128 k]
  const float* b1;
  const float* b2;
  const float* gam;
  const float* bet;
  int nRows;
};

__device__ __forceinline__ short f2b(float f) {
  unsigned int u = __float_as_uint(f);
  u = (u + 0x7fffu + ((u >> 16) & 1u)) >> 16;
  return (short)u;
}
__device__ __forceinline__ unsigned int cvtpk(float lo, float hi) {
  unsigned int r;
  asm("v_cvt_pk_bf16_f32 %0, %1, %2" : "=v"(r) : "v"(lo), "v"(hi));
  return r;
}
__device__ __forceinline__ bf16x8 pack8(float4 a, float4 b) {
  union { unsigned int u[4]; bf16x8 s; } x;
  x.u[0] = cvtpk(a.x, a.y); x.u[1] = cvtpk(a.z, a.w);
  x.u[2] = cvtpk(b.x, b.y); x.u[3] = cvtpk(b.z, b.w);
  return x.s;
}

// BK=128 restructure of the proven R6/R8 cooperative kernel.
// Evidence: R6≈R2 (halving per-iter work: no gain), R9 (deeper prefetch: no
// gain), R8/R10 (more occupancy: no gain/worse) => cost is a FIXED latency
// exposure per barrier-iteration with shallow per-thread MLP. Fix: 3 fat
// phase-1 iterations (6 barriers vs 24), 16 back-to-back float4 loads per
// thread per stage (16-deep MLP), one full-K phase-2 chunk. H aliases Abuf,
// W2 aliases Wst. Numerics identical to R8 (absmax 0.0703 expected).
template<bool IS_EDGE>
__launch_bounds__(256, 2)
__global__ void mlp_kernel(MlpParams pmA, MlpParams pmB, int blocksA) {
  const bool isA = (int)blockIdx.x < blocksA;
  const MlpParams P = isA ? pmA : pmB;
  const int bid  = isA ? (int)blockIdx.x : (int)blockIdx.x - blocksA;
  const int row0 = bid * 128;

  __shared__ __align__(16) short Hbuf[128][136];  // A chunk / H (aliased)
  __shared__ __align__(16) short Wst[128][136];   // W1 chunk / W2 (aliased)
  __shared__ float b1s[128], b2s[128], gs[128], bes[128];
  __shared__ int   idxa[128], idxb[128];
  __shared__ float inv1s[128], inv2s[128];
  __shared__ float sumL[2][128], sqL[2][128];
  __shared__ float muL[128], rsL[128];

  const int t = threadIdx.x;

  if (t < 128) {
    b1s[t] = P.b1[t];
    gs[t]  = P.gam[t];
    if (IS_EDGE) {
      int r = row0 + t;
      idxa[t] = (r < P.nRows) ? P.src[r] : 0;
    } else {
      int r = min(row0 + t, P.nRows - 1);
      inv1s[t] = P.inv1[r];
    }
  } else {
    int t2 = t - 128;
    b2s[t2] = P.b2[t2];
    bes[t2] = P.bet[t2];
    if (IS_EDGE) {
      int r = row0 + t2;
      idxb[t2] = (r < P.nRows) ? P.dst[r] : 0;
    } else {
      int r = min(row0 + t2, P.nRows - 1);
      inv2s[t2] = P.inv2[r];
    }
  }
  __syncthreads();   // idx/inv tables ready

  const int l   = t & 63;
  const int wid = t >> 6;
  const int wr  = wid >> 1, wcc = wid & 1;
  const int lr  = l & 15,  lg  = l >> 4;

  const int  srow  = t >> 1, sh = t & 1;   // staging: 2 threads/row, 64 f32 each
  const int  sgRow = row0 + srow;
  const bool sval  = sgRow < P.nRows;
  const int  sgC   = sval ? sgRow : 0;
  const float vmask = sval ? 1.f : 0.f;

  // per-thread A base pointers for the 3 K-segments (each = one BK=128 chunk)
  const float* base0; const float* base1; const float* base2;
  float sc1v = vmask, sc2v = vmask;
  if (IS_EDGE) {
    base0 = P.x + (size_t)idxa[srow] * LDIM + sh * 64;
    base1 = P.x + (size_t)idxb[srow] * LDIM + sh * 64;
    base2 = P.attrIn + (size_t)sgC * LDIM + sh * 64;
  } else {
    base0 = P.x    + (size_t)sgC * LDIM + sh * 64;
    base1 = P.sum1 + (size_t)sgC * LDIM + sh * 64;
    base2 = P.sum2 + (size_t)sgC * LDIM + sh * 64;
    sc1v = inv1s[srow] * vmask;
    sc2v = inv2s[srow] * vmask;
  }

  // weight staging: 2 threads/row, 64 bf16 (128B) contiguous each
  const int wrow = t >> 1, wsh = t & 1;
  const short* w1base = P.W1H + (size_t)wrow * 384 + wsh * 64;

  f32x4 acc[4][4];
#pragma unroll
  for (int i = 0; i < 4; ++i)
#pragma unroll
    for (int j = 0; j < 4; ++j) acc[i][j] = f32x4{0.f, 0.f, 0.f, 0.f};

  // ---------------- phase 1: H = relu(A @ W1 + b1), 3 x BK=128 ----------------
#pragma unroll
  for (int kc = 0; kc < 3; ++kc) {
    // ---- stage A chunk: 16 back-to-back float4 loads (deep MLP) ----
    {
      const float* abase = (kc == 0) ? base0 : (kc == 1) ? base1 : base2;
      const float scK = (kc == 0) ? vmask : (kc == 1) ? sc1v : sc2v;
      float4 av4[16];
#pragma unroll
      for (int j = 0; j < 16; ++j) av4[j] = ((const float4*)abase)[j];
      if (scK != 1.0f) {
#pragma unroll
        for (int j = 0; j < 16; ++j) {
          av4[j].x *= scK; av4[j].y *= scK; av4[j].z *= scK; av4[j].w *= scK;
        }
      }
      if constexpr (!IS_EDGE) {
        if (kc != 0 && sval) {   // zero-after-read (each element owned by one thread)
          float4 z = {0.f, 0.f, 0.f, 0.f};
#pragma unroll
          for (int j = 0; j < 16; ++j) ((float4*)abase)[j] = z;
        }
      }
#pragma unroll
      for (int j = 0; j < 8; ++j)
        *(bf16x8*)&Hbuf[srow][sh * 64 + j * 8] = pack8(av4[2 * j], av4[2 * j + 1]);
    }
    // ---- stage W1 chunk: 8 contiguous 16B loads ----
    {
      const short* wsrc = w1base + kc * 128;
      bf16x8 wv[8];
#pragma unroll
      for (int j = 0; j < 8; ++j) wv[j] = *(const bf16x8*)(wsrc + j * 8);
#pragma unroll
      for (int j = 0; j < 8; ++j)
        *(bf16x8*)&Wst[wrow][wsh * 64 + j * 8] = wv[j];
    }
    __syncthreads();   // chunk ready
    // ---- 64 MFMAs over BK=128 ----
#pragma unroll
    for (int kk = 0; kk < 4; ++kk) {
      bf16x8 av[4], bh[4];
#pragma unroll
      for (int mi = 0; mi < 4; ++mi)
        av[mi] = *(const bf16x8*)&Hbuf[wr * 64 + mi * 16 + lr][kk * 32 + lg * 8];
#pragma unroll
      for (int ni = 0; ni < 4; ++ni)
        bh[ni] = *(const bf16x8*)&Wst[wcc * 64 + ni * 16 + lr][kk * 32 + lg * 8];
#pragma unroll
      for (int mi = 0; mi < 4; ++mi)
#pragma unroll
        for (int ni = 0; ni < 4; ++ni)
          acc[mi][ni] = __builtin_amdgcn_mfma_f32_16x16x32_bf16(av[mi], bh[ni], acc[mi][ni], 0, 0, 0);
    }
    __syncthreads();   // reads done: buffers overwritable
  }

  // preload all of W2 into regs (consumed after H-write; flies over the VALU)
  const short* w2base = P.W2H + (size_t)wrow * 128 + wsh * 64;
  bf16x8 w2v[8];
#pragma unroll
  for (int j = 0; j < 8; ++j) w2v[j] = *(const bf16x8*)(w2base + j * 8);

  // write H = relu(acc + b1) into Hbuf (acc dies here — R7 lesson)
#pragma unroll
  for (int rt = 0; rt < 4; ++rt)
#pragma unroll
    for (int ct = 0; ct < 4; ++ct) {
      const int cc = wcc * 64 + ct * 16 + lr;
      const float bb = b1s[cc];
#pragma unroll
      for (int q = 0; q < 4; ++q) {
        const int rr = wr * 64 + rt * 16 + lg * 4 + q;
        Hbuf[rr][cc] = f2b(fmaxf(acc[rt][ct][q] + bb, 0.f));
      }
    }
  // stage full W2 into Wst
#pragma unroll
  for (int j = 0; j < 8; ++j)
    *(bf16x8*)&Wst[wrow][wsh * 64 + j * 8] = w2v[j];
  __syncthreads();

  // ---------------- phase 2: OUT = H @ W2 + b2, single K=128 chunk ----------------
  f32x4 acc2[4][4];
#pragma unroll
  for (int i = 0; i < 4; ++i)
#pragma unroll
    for (int j = 0; j < 4; ++j) acc2[i][j] = f32x4{0.f, 0.f, 0.f, 0.f};

#pragma unroll
  for (int kk = 0; kk < 4; ++kk) {
    bf16x8 av2[4], bh2[4];
#pragma unroll
    for (int rt = 0; rt < 4; ++rt)
      av2[rt] = *(const bf16x8*)&Hbuf[wr * 64 + rt * 16 + lr][kk * 32 + lg * 8];
#pragma unroll
    for (int ct = 0; ct < 4; ++ct)
      bh2[ct] = *(const bf16x8*)&Wst[wcc * 64 + ct * 16 + lr][kk * 32 + lg * 8];
#pragma unroll
    for (int rt = 0; rt < 4; ++rt)
#pragma unroll
      for (int ct = 0; ct < 4; ++ct)
        acc2[rt][ct] = __builtin_amdgcn_mfma_f32_16x16x32_bf16(av2[rt], bh2[ct], acc2[rt][ct], 0, 0, 0);
  }

  // ---------------- f32 epilogue: b2 + LN stats from registers (R8 verbatim) ----------------
  float s1[4][4], s2[4][4];
#pragma unroll
  for (int rt = 0; rt < 4; ++rt)
#pragma unroll
    for (int q = 0; q < 4; ++q) { s1[rt][q] = 0.f; s2[rt][q] = 0.f; }
#pragma unroll
  for (int rt = 0; rt < 4; ++rt)
#pragma unroll
    for (int ct = 0; ct < 4; ++ct) {
      const float bb = b2s[wcc * 64 + ct * 16 + lr];
#pragma unroll
      for (int q = 0; q < 4; ++q) {
        float v = acc2[rt][ct][q] + bb;
        acc2[rt][ct][q] = v;
        s1[rt][q] += v;
        s2[rt][q] += v * v;
      }
    }
#pragma unroll
  for (int m = 1; m < 16; m <<= 1) {
#pragma unroll
    for (int rt = 0; rt < 4; ++rt)
#pragma unroll
      for (int q = 0; q < 4; ++q) {
        s1[rt][q] += __shfl_xor(s1[rt][q], m);
        s2[rt][q] += __shfl_xor(s2[rt][q], m);
      }
  }
  __syncthreads();
  {
    const int rt = lr >> 2, q = lr & 3;
    const int rr = wr * 64 + rt * 16 + lg * 4 + q;
    sumL[wcc][rr] = s1[rt][q];
    sqL[wcc][rr]  = s2[rt][q];
  }
  __syncthreads();
  if (t < 128) {
    const float tot = sumL[0][t] + sumL[1][t];
    const float tsq = sqL[0][t] + sqL[1][t];
    const float mu  = tot * (1.0f / 128.0f);
    const float var = tsq * (1.0f / 128.0f) - mu * mu;
    muL[t] = mu;
    rsL[t] = rsqrtf(var + 1e-5f);
  }
  __syncthreads();

  // ---------------- normalize + residual + store + (edge) scatter-add ----------------
#pragma unroll
  for (int rt = 0; rt < 4; ++rt) {
#pragma unroll
    for (int q = 0; q < 4; ++q) {
      const int rr = wr * 64 + rt * 16 + lg * 4 + q;
      const int grow = row0 + rr;
      if (grow < P.nRows) {
        const float mu = muL[rr], rs = rsL[rr];
        const float* rin = P.attrIn + (size_t)grow * LDIM;
        float* rout = P.attrOut + (size_t)grow * LDIM;
        float* ssum = nullptr;
        if (IS_EDGE) ssum = P.sum1 + (size_t)idxb[rr] * LDIM;
#pragma unroll
        for (int ct = 0; ct < 4; ++ct) {
          const int cc = wcc * 64 + ct * 16 + lr;
          const float o = gs[cc] * (acc2[rt][ct][q] - mu) * rs + bes[cc] + rin[cc];
          rout[cc] = o;
          if (IS_EDGE) atomicAdd(ssum + cc, o);
        }
      }
    }
  }
}

// ---- prep kernels ----
__global__ void prep_weights(const float* w1a, const float* w1b, const float* w1c,
                             const float* w2a, const float* w2b, const float* w2c,
                             short* w1h, short* w2h) {
  int i = blockIdx.x * 256 + threadIdx.x;
  constexpr int N1 = 18 * 128 * 384;
  constexpr int N2 = 18 * 128 * 128;
  if (i < N1) {
    int g = i / (128 * 384);
    int rem = i - g * (128 * 384);
    int n = rem / 384, k = rem - n * 384;
    int m = g / 6, s = g - m * 6;
    const float* src = (m == 0) ? w1a : (m == 1) ? w1b : w1c;
    w1h[i] = f2b(src[(size_t)s * (384 * 128) + (size_t)k * 128 + n]);
  } else if (i < N1 + N2) {
    int j = i - N1;
    int g = j / (128 * 128);
    int rem = j - g * (128 * 128);
    int n = rem / 128, k = rem - n * 128;
    int m = g / 6, s = g - m * 6;
    const float* src = (m == 0) ? w2a : (m == 1) ? w2b : w2c;
    w2h[j] = f2b(src[(size_t)s * (128 * 128) + (size_t)k * 128 + n]);
  }
}

__global__ void prep_deg(const int* mr, const int* wrcv, int* degm, int* degw) {
  int i = blockIdx.x * 256 + threadIdx.x;
  if (i < EM_N) atomicAdd(&degm[mr[i]], 1);
  else if (i < EM_N + EW_N) atomicAdd(&degw[wrcv[i - EM_N]], 1);
}

__global__ void prep_inv(const int* degm, const int* degw, float* invm, float* invw) {
  int i = blockIdx.x * 256 + threadIdx.x;
  if (i < NNODE) {
    invm[i] = 1.0f / fmaxf((float)degm[i], 1.0f);
    invw[i] = 1.0f / fmaxf((float)degw[i], 1.0f);
  }
}

extern "C" void kernel_launch(void* const* d_in, const int* in_sizes, int n_in,
                              void* d_out, int out_size, void* d_ws, size_t ws_size,
                              hipStream_t stream) {
  (void)in_sizes; (void)n_in; (void)out_size; (void)ws_size;
  const float* x_in   = (const float*)d_in[0];
  const float* mea_in = (const float*)d_in[1];
  const float* wea_in = (const float*)d_in[2];
  const int*   mei    = (const int*)d_in[3];
  const int*   wei    = (const int*)d_in[4];
  const float* W1s[3] = { (const float*)d_in[5],  (const float*)d_in[11], (const float*)d_in[17] };
  const float* B1s[3] = { (const float*)d_in[6],  (const float*)d_in[12], (const float*)d_in[18] };
  const float* W2s[3] = { (const float*)d_in[7],  (const float*)d_in[13], (const float*)d_in[19] };
  const float* B2s[3] = { (const float*)d_in[8],  (const float*)d_in[14], (const float*)d_in[20] };
  const float* Gs[3]  = { (const float*)d_in[9],  (const float*)d_in[15], (const float*)d_in[21] };
  const float* Be[3]  = { (const float*)d_in[10], (const float*)d_in[16], (const float*)d_in[22] };

  float* xo  = (float*)d_out;
  float* meo = xo  + (size_t)NNODE * LDIM;
  float* weo = meo + (size_t)EM_N * LDIM;

  float* msum = (float*)d_ws;
  float* wsum = msum + (size_t)NNODE * LDIM;
  int*   degm = (int*)(wsum + (size_t)NNODE * LDIM);
  int*   degw = degm + NNODE;
  float* invm = (float*)(degw + NNODE);
  float* invw = invm + NNODE;
  short* w1h  = (short*)(invw + NNODE);
  short* w2h  = w1h + (size_t)18 * 128 * 384;

  size_t zbytes = (size_t)2 * NNODE * LDIM * 4 + (size_t)2 * NNODE * 4;
  hipMemsetAsync(d_ws, 0, zbytes, stream);

  {
    int tot = 18 * 128 * 384 + 18 * 128 * 128;
    prep_weights<<<dim3((tot + 255) / 256), 256, 0, stream>>>(
        W1s[0], W1s[1], W1s[2], W2s[0], W2s[1], W2s[2], w1h, w2h);
  }
  prep_deg<<<dim3((EM_N + EW_N + 255) / 256), 256, 0, stream>>>(mei + EM_N, wei + EW_N, degm, degw);
  prep_inv<<<dim3((NNODE + 255) / 256), 256, 0, stream>>>(degm, degw, invm, invw);

  const int MB = (EM_N + 127) / 128;   // 782
  const int WB = (EW_N + 127) / 128;   // 196
  const int NB = (NNODE + 127) / 128;  // 157

  const float* xc = x_in;
  const float* mc = mea_in;
  const float* wc = wea_in;

  for (int s = 0; s < NSTEP; ++s) {
    MlpParams pm{}, pw{}, pn{};

    pm.x = xc; pm.attrIn = mc; pm.attrOut = meo;
    pm.src = mei; pm.dst = mei + EM_N;
    pm.sum1 = msum;
    pm.W1H = w1h + (size_t)(0 * 6 + s) * 128 * 384;
    pm.W2H = w2h + (size_t)(0 * 6 + s) * 128 * 128;
    pm.b1 = B1s[0] + s * LDIM; pm.b2 = B2s[0] + s * LDIM;
    pm.gam = Gs[0] + s * LDIM; pm.bet = Be[0] + s * LDIM;
    pm.nRows = EM_N;

    pw.x = xc; pw.attrIn = wc; pw.attrOut = weo;
    pw.src = wei; pw.dst = wei + EW_N;
    pw.sum1 = wsum;
    pw.W1H = w1h + (size_t)(1 * 6 + s) * 128 * 384;
    pw.W2H = w2h + (size_t)(1 * 6 + s) * 128 * 128;
    pw.b1 = B1s[1] + s * LDIM; pw.b2 = B2s[1] + s * LDIM;
    pw.gam = Gs[1] + s * LDIM; pw.bet = Be[1] + s * LDIM;
    pw.nRows = EW_N;

    mlp_kernel<true><<<dim3(MB + WB), 256, 0, stream>>>(pm, pw, MB);

    pn.x = xc; pn.attrIn = xc; pn.attrOut = xo;
    pn.sum1 = msum; pn.sum2 = wsum; pn.inv1 = invm; pn.inv2 = invw;
    pn.W1H = w1h + (size_t)(2 * 6 + s) * 128 * 384;
    pn.W2H = w2h + (size_t)(2 * 6 + s) * 128 * 128;
    pn.b1 = B1s[2] + s * LDIM; pn.b2 = B2s[2] + s * LDIM;
    pn.gam = Gs[2] + s * LDIM; pn.bet = Be[2] + s * LDIM;
    pn.nRows = NNODE;

    mlp_kernel<false><<<dim3(NB), 256, 0, stream>>>(pn, pn, NB);

    xc = xo; mc = meo; wc = weo;
  }
}